// Round 6
// baseline (359.097 us; speedup 1.0000x reference)
//
#include <hip/hip_runtime.h>
#include <hip/hip_bf16.h>

// RecurrentDecoder: B=256,N=128,D=256,Z=64,H=128, pred_len=30
// Rank-2 fold (verified R4): gate args accumulate entirely in MFMA.
//   W~[j] = scl_j*W_hh[j] + P2Gs0[j]*Wout[0] + P2Gs1[j]*Wout[1]
//   K-slots 128,129 of state rows hold pos_{t-1}(bf16); cvec carries b_out*P2Gs.
// R6: identical structure to R5, but amdgpu_waves_per_eu(2,2) pins the
// allocator at 2 waves/EU (VGPR budget 256) so the ~220-reg working set
// stays in registers instead of spilling ~60 regs/thread to scratch
// (R5: WRITE_SIZE 42.8MB vs 7.9MB output = 35MB spill traffic).

#define T_LEN 30
#define H_    128
#define G3_   384
#define KIN_  320
#define S2B   272                 // bytes per state row (136 bf16 elems, 130 used)
#define HB    (128*S2B)           // 34816 per ping-pong buffer
#define TRAJ_OFF (2*HB)           // 69632
#define LDS_BYTES (TRAJ_OFF + T_LEN*128*8)  // 100352

#define SCL_RZ -1.44269504088896341f
#define SCL_N   2.88539008177792681f

typedef float  f32x4 __attribute__((ext_vector_type(4)));
typedef __bf16 b16x8 __attribute__((ext_vector_type(8)));
typedef unsigned u32x4 __attribute__((ext_vector_type(4)));

#define MFMA16(a,b,c) __builtin_amdgcn_mfma_f32_16x16x32_bf16((a),(b),(c),0,0,0)

__device__ __forceinline__ b16x8 pack8s(const float* p, float s){
  b16x8 r;
  #pragma unroll
  for (int i=0;i<8;i++) r[i] = (__bf16)(s*p[i]);
  return r;
}
__device__ __forceinline__ unsigned pk2(float a, float b){
  __bf16 x=(__bf16)a, y=(__bf16)b;
  unsigned short ux=__builtin_bit_cast(unsigned short,x);
  unsigned short uy=__builtin_bit_cast(unsigned short,y);
  return (unsigned)ux | ((unsigned)uy<<16);
}
__device__ __forceinline__ f32x4 unpk2(unsigned lo, unsigned hi){
  f32x4 r;
  r[0]=__builtin_bit_cast(float, lo<<16);
  r[1]=__builtin_bit_cast(float, lo&0xFFFF0000u);
  r[2]=__builtin_bit_cast(float, hi<<16);
  r[3]=__builtin_bit_cast(float, hi&0xFFFF0000u);
  return r;
}
__device__ __forceinline__ b16x8 fragu(unsigned v){
  u32x4 t = {v,0u,0u,0u};
  return __builtin_bit_cast(b16x8, t);
}

// ---- prep 1: WcT[j][k] = scl_j * sum_m W_in[k][m]*W_ih[j][m]  (384x320 bf16) ----
__global__ void prep_wc(const float* __restrict__ W_in, const float* __restrict__ W_ih,
                        __bf16* __restrict__ WcT){
  __shared__ float win[H_][16];
  int k0 = blockIdx.x << 4;
  for (int i=threadIdx.x; i<16*H_; i+=384){
    int kk = i>>7, m = i&127;
    win[m][kk] = W_in[(size_t)(k0+kk)*H_ + m];
  }
  __syncthreads();
  int j = threadIdx.x;
  const float* wr = W_ih + (size_t)j*H_;
  float acc[16];
  #pragma unroll
  for (int kk=0;kk<16;kk++) acc[kk]=0.f;
  for (int m=0;m<H_;m++){
    float wv = wr[m];
    #pragma unroll
    for (int kk=0;kk<16;kk++) acc[kk] = fmaf(wv, win[m][kk], acc[kk]);
  }
  float scl = (j < 2*H_) ? SCL_RZ : SCL_N;
  #pragma unroll
  for (int kk=0;kk<16;kk++) WcT[(size_t)j*KIN_ + k0 + kk] = (__bf16)(scl*acc[kk]);
}

// ---- prep 2: cvec'(b_out-folded), P2Gs (scaled) ----
__global__ void prep_vec(const float* __restrict__ W_in, const float* __restrict__ b_in,
                         const float* __restrict__ W_ih, const float* __restrict__ b_ih,
                         const float* __restrict__ b_hh, const float* __restrict__ b_out,
                         float* __restrict__ cvec, float* __restrict__ P2G){
  int j = threadIdx.x;                      // 0..383
  const float* wr = W_ih + (size_t)j*H_;
  float s  = b_ih[j] + (j < 2*H_ ? b_hh[j] : 0.f);
  float p0 = 0.f, p1 = 0.f;
  #pragma unroll 8
  for (int m=0;m<H_;m++){
    float wv = wr[m];
    s  += b_in[m]*wv;
    p0 += W_in[(size_t)KIN_*H_ + m]*wv;
    p1 += W_in[(size_t)(KIN_+1)*H_ + m]*wv;
  }
  float scl = (j < 2*H_) ? SCL_RZ : SCL_N;
  float p0s = scl*p0, p1s = scl*p1;
  P2G[j] = p0s; P2G[G3_ + j] = p1s;
  cvec[j] = scl*s + b_out[0]*p0s + b_out[1]*p1s;   // b_out*P2G fold
}

// ---- prep 3: WT[512][136] bf16 — sets {0:r,1:z,2:an,3:inn} ----
__global__ void prep_wt(const float* __restrict__ W_hh, const float* __restrict__ W_out,
                        const float* __restrict__ P2G, __bf16* __restrict__ WT){
  int jp = blockIdx.x;                 // 0..511
  int set = jp >> 7, col = jp & 127;
  int j = (set==0) ? col : (set==1) ? H_+col : 2*H_+col;
  float p0 = P2G[j], p1 = P2G[G3_+j];  // scaled
  int k = threadIdx.x;
  if (k >= 136) return;
  float v = 0.f;
  if (k < 128){
    if (set<=1)      v = SCL_RZ*W_hh[(size_t)j*H_+k] + p0*W_out[k] + p1*W_out[H_+k];
    else if (set==2) v = SCL_N *W_hh[(size_t)j*H_+k];
    else             v = p0*W_out[k] + p1*W_out[H_+k];
  } else if (k==128){ v = (set==2)? 0.f : p0; }
  else if (k==129){ v = (set==2)? 0.f : p1; }
  WT[(size_t)jp*136 + k] = (__bf16)v;
}

// ---- decoder: 256 blocks x 512 threads, 128 rows/block (one batch b each) ----
__global__ void __attribute__((amdgpu_flat_work_group_size(512,512),
                               amdgpu_waves_per_eu(2,2)))
decoder(const float* __restrict__ h_obs, const float* __restrict__ zin,
        const float* __restrict__ start_pos,
        const float* __restrict__ b_hh, const float* __restrict__ W_out,
        const float* __restrict__ b_out,
        const __bf16* __restrict__ WcT, const float* __restrict__ cvec,
        const __bf16* __restrict__ WT, float* __restrict__ out)
{
  __shared__ __align__(16) char lds[LDS_BYTES];
  __bf16* stg = (__bf16*)lds;                 // [128][328] prologue staging

  const int tid  = threadIdx.x;
  const int lane = tid & 63;
  const int w    = tid >> 6;
  const int l15  = lane & 15;
  const int lhi  = lane >> 4;
  const int R0   = blockIdx.x << 7;           // 128 rows per block
  const int hcol = (w<<4) + l15;
  const int jr = hcol, jz = H_ + hcol, jn = 2*H_ + hcol;
  const int oc = l15 & 1;
  const int gd = w >> 1, md = w & 1;          // this wave's delta slice

  // ---- stage base tile (128 x 320 f32 -> bf16, stride 328) ----
  {
    const float4* src = reinterpret_cast<const float4*>(h_obs) + (size_t)R0*64;
    #pragma unroll
    for (int i=0;i<16;i++){
      int k = tid + (i<<9);
      float4 v = src[k];
      int r = k>>6, c = (k&63)<<2;
      __bf16* d = &stg[r*328 + c];
      d[0]=(__bf16)v.x; d[1]=(__bf16)v.y; d[2]=(__bf16)v.z; d[3]=(__bf16)v.w;
    }
    const float4* srcz = reinterpret_cast<const float4*>(zin) + (size_t)R0*16;
    #pragma unroll
    for (int i=0;i<4;i++){
      int k = tid + (i<<9);
      float4 v = srcz[k];
      int r = k>>4, c = 256 + ((k&15)<<2);
      __bf16* d = &stg[r*328 + c];
      d[0]=(__bf16)v.x; d[1]=(__bf16)v.y; d[2]=(__bf16)v.z; d[3]=(__bf16)v.w;
    }
  }

  // ---- scalar constants ----
  const float bo0 = b_out[0], bo1 = b_out[1];
  const float bo  = oc ? bo1 : bo0;
  const float bhn = SCL_N * b_hh[2*H_ + hcol];
  const f32x4 bhnvec = (f32x4){bhn,bhn,bhn,bhn};
  const f32x4 bovec  = (f32x4){bo,bo,bo,bo};

  // ---- fp32 pos master: wave w owns rows gd*32+md*16+lhi*4+q ----
  float px[4], py[4];
  #pragma unroll
  for (int q=0;q<4;q++){
    int r = R0 + (gd<<5) + (md<<4) + (lhi<<2) + q;
    px[q] = start_pos[2*r]   - bo0;
    py[q] = start_pos[2*r+1] - bo1;
  }

  __syncthreads();

  // ---- prologue: G[g] = base @ Wc + cvec' (K=320), pack to bf16 pairs ----
  unsigned Gp[4][3][2][2];
  {
    f32x4 G[4][3][2];
    float cr = cvec[jr], cz = cvec[jz], cn = cvec[jn];
    #pragma unroll
    for (int g=0; g<4; g++){
      G[g][0][0] = (f32x4){cr,cr,cr,cr}; G[g][0][1] = G[g][0][0];
      G[g][1][0] = (f32x4){cz,cz,cz,cz}; G[g][1][1] = G[g][1][0];
      G[g][2][0] = (f32x4){cn,cn,cn,cn}; G[g][2][1] = G[g][2][0];
    }
    #pragma unroll 1
    for (int kk=0; kk<10; kk++){
      const int ko = (kk<<5) + (lhi<<3);
      b16x8 br = *reinterpret_cast<const b16x8*>(WcT + (size_t)jr*KIN_ + ko);
      b16x8 bz = *reinterpret_cast<const b16x8*>(WcT + (size_t)jz*KIN_ + ko);
      b16x8 bn = *reinterpret_cast<const b16x8*>(WcT + (size_t)jn*KIN_ + ko);
      #pragma unroll
      for (int g=0; g<4; g++){
        b16x8 a0 = *reinterpret_cast<const b16x8*>(&stg[(g*32   +l15)*328 + ko]);
        b16x8 a1 = *reinterpret_cast<const b16x8*>(&stg[(g*32+16+l15)*328 + ko]);
        G[g][0][0] = MFMA16(a0, br, G[g][0][0]); G[g][0][1] = MFMA16(a1, br, G[g][0][1]);
        G[g][1][0] = MFMA16(a0, bz, G[g][1][0]); G[g][1][1] = MFMA16(a1, bz, G[g][1][1]);
        G[g][2][0] = MFMA16(a0, bn, G[g][2][0]); G[g][2][1] = MFMA16(a1, bn, G[g][2][1]);
      }
    }
    #pragma unroll
    for (int g=0; g<4; g++)
      #pragma unroll
      for (int gate=0; gate<3; gate++)
        #pragma unroll
        for (int m=0; m<2; m++){
          Gp[g][gate][m][0] = pk2(G[g][gate][m][0], G[g][gate][m][1]);
          Gp[g][gate][m][1] = pk2(G[g][gate][m][2], G[g][gate][m][3]);
        }
  }

  // ---- persistent B-fragments (after G to lower prologue pressure) ----
  b16x8 Br[4],Bz[4],Ban[4],Binn[4],Bo[4];
  #pragma unroll
  for (int kk=0;kk<4;kk++){
    const int ko = kk*32 + lhi*8;
    Br[kk]   = *reinterpret_cast<const b16x8*>(WT + (size_t)(      hcol)*136 + ko);
    Bz[kk]   = *reinterpret_cast<const b16x8*>(WT + (size_t)(128 + hcol)*136 + ko);
    Ban[kk]  = *reinterpret_cast<const b16x8*>(WT + (size_t)(256 + hcol)*136 + ko);
    Binn[kk] = *reinterpret_cast<const b16x8*>(WT + (size_t)(384 + hcol)*136 + ko);
    Bo[kk]   = pack8s(W_out + (size_t)oc*H_ + ko, 1.0f);
  }
  const b16x8 Br4 = fragu(lhi==0 ? *reinterpret_cast<const unsigned*>(WT + (size_t)(      hcol)*136 + 128) : 0u);
  const b16x8 Bz4 = fragu(lhi==0 ? *reinterpret_cast<const unsigned*>(WT + (size_t)(128 + hcol)*136 + 128) : 0u);
  const b16x8 Bi4 = fragu(lhi==0 ? *reinterpret_cast<const unsigned*>(WT + (size_t)(384 + hcol)*136 + 128) : 0u);

  __syncthreads();   // staging dead

  // ---- init buf0: zero h slots, owners write pos slots ----
  for (int i=tid; i<8192; i+=512){
    int r = i>>6, dw = i&63;
    *reinterpret_cast<unsigned*>(lds + r*S2B + dw*4) = 0u;
  }
  if (l15==0){
    #pragma unroll
    for (int q=0;q<4;q++){
      int row = (gd<<5) + (md<<4) + (lhi<<2) + q;
      *reinterpret_cast<unsigned*>(lds + row*S2B + 256) = pk2(px[q], py[q]);
    }
  }

  float st[4][2][4];
  #pragma unroll
  for (int g=0;g<4;g++)
    #pragma unroll
    for (int m=0;m<2;m++)
      #pragma unroll
      for (int q=0;q<4;q++) st[g][m][q] = 0.f;

  const unsigned rdb = (unsigned)(l15*S2B + lhi*16);

  int cur = 0;
  #pragma unroll 1
  for (int t=0; t<T_LEN; ++t){
    __syncthreads();
    const char* rb = lds + cur*HB;
    char*       wb = lds + (cur^1)*HB;

    #pragma unroll
    for (int g=0; g<4; ++g){
      const char* rg_ = rb + g*(32*S2B);
      char*       wg_ = wb + g*(32*S2B);
      const bool own = (gd == g);

      f32x4 ar0 = unpk2(Gp[g][0][0][0], Gp[g][0][0][1]);
      f32x4 ar1 = unpk2(Gp[g][0][1][0], Gp[g][0][1][1]);
      f32x4 az0 = unpk2(Gp[g][1][0][0], Gp[g][1][0][1]);
      f32x4 az1 = unpk2(Gp[g][1][1][0], Gp[g][1][1][1]);
      f32x4 ai0 = unpk2(Gp[g][2][0][0], Gp[g][2][0][1]);
      f32x4 ai1 = unpk2(Gp[g][2][1][0], Gp[g][2][1][1]);
      f32x4 an0 = bhnvec, an1 = bhnvec;
      f32x4 dAcc = bovec;

      #pragma unroll
      for (int kk=0;kk<4;kk++){
        b16x8 a0 = *reinterpret_cast<const b16x8*>(rg_ + rdb + kk*64);
        b16x8 a1 = *reinterpret_cast<const b16x8*>(rg_ + rdb + 16*S2B + kk*64);
        ar0 = MFMA16(a0,Br[kk],ar0);   ar1 = MFMA16(a1,Br[kk],ar1);
        az0 = MFMA16(a0,Bz[kk],az0);   az1 = MFMA16(a1,Bz[kk],az1);
        an0 = MFMA16(a0,Ban[kk],an0);  an1 = MFMA16(a1,Ban[kk],an1);
        ai0 = MFMA16(a0,Binn[kk],ai0); ai1 = MFMA16(a1,Binn[kk],ai1);
        if (own){
          b16x8 am = md ? a1 : a0;     // wave-uniform select
          dAcc = MFMA16(am, Bo[kk], dAcc);
        }
      }
      {
        unsigned pp0 = *reinterpret_cast<const unsigned*>(rg_ + l15*S2B + 256);
        unsigned pp1 = *reinterpret_cast<const unsigned*>(rg_ + (16+l15)*S2B + 256);
        b16x8 a40 = fragu(lhi==0 ? pp0 : 0u);
        b16x8 a41 = fragu(lhi==0 ? pp1 : 0u);
        ar0 = MFMA16(a40,Br4,ar0); ar1 = MFMA16(a41,Br4,ar1);
        az0 = MFMA16(a40,Bz4,az0); az1 = MFMA16(a41,Bz4,az1);
        ai0 = MFMA16(a40,Bi4,ai0); ai1 = MFMA16(a41,Bi4,ai1);
      }

      if (own){
        // pos += delta for this wave's 16 rows
        #pragma unroll
        for (int q=0;q<4;q++){
          float dme  = dAcc[q];
          float doth = __shfl_xor(dme, 1);
          px[q] += oc ? doth : dme;
          py[q] += oc ? dme  : doth;
        }
        if (l15==0){
          #pragma unroll
          for (int q=0;q<4;q++){
            int row = (gd<<5) + (md<<4) + (lhi<<2) + q;
            if (t > 0){
              float2 v; v.x = px[q]; v.y = py[q];
              *reinterpret_cast<float2*>(lds + TRAJ_OFF + ((t-1)*128 + row)*8) = v;
            }
            *reinterpret_cast<unsigned*>(wb + row*S2B + 256) = pk2(px[q], py[q]);
          }
        }
      }

      // gates -> h_{t+1}
      #pragma unroll
      for (int m=0;m<2;m++){
        f32x4 Ar = m? ar1:ar0, Az = m? az1:az0, An = m? an1:an0, Ai = m? ai1:ai0;
        #pragma unroll
        for (int q=0;q<4;q++){
          float rgt = __builtin_amdgcn_rcpf(1.f + __builtin_amdgcn_exp2f(Ar[q]));
          float zgt = __builtin_amdgcn_rcpf(1.f + __builtin_amdgcn_exp2f(Az[q]));
          float na  = fmaf(rgt, An[q], Ai[q]);
          float nn  = fmaf(-2.f, __builtin_amdgcn_rcpf(1.f + __builtin_amdgcn_exp2f(na)), 1.f);
          float h   = fmaf(zgt, st[g][m][q] - nn, nn);
          st[g][m][q] = h;
          *reinterpret_cast<__bf16*>(wg_ + ((m<<4)+(lhi<<2)+q)*S2B + hcol*2) = (__bf16)h;
        }
      }
    }
    cur ^= 1;
  }

  // ---- epilogue: final delta -> traj[29] ----
  __syncthreads();
  {
    const char* rg_ = lds + cur*HB + gd*(32*S2B);
    const unsigned dbase = (unsigned)((md*16 + l15)*S2B + lhi*16);
    f32x4 d = bovec;
    #pragma unroll
    for (int kk=0;kk<4;kk++){
      b16x8 fk = *reinterpret_cast<const b16x8*>(rg_ + dbase + kk*64);
      d = MFMA16(fk, Bo[kk], d);
    }
    #pragma unroll
    for (int q=0;q<4;q++){
      float dme  = d[q];
      float doth = __shfl_xor(dme, 1);
      px[q] += oc ? doth : dme;
      py[q] += oc ? dme  : doth;
    }
    if (l15==0){
      #pragma unroll
      for (int q=0;q<4;q++){
        int row = (gd<<5) + (md<<4) + (lhi<<2) + q;
        float2 v; v.x = px[q]; v.y = py[q];
        *reinterpret_cast<float2*>(lds + TRAJ_OFF + ((T_LEN-1)*128 + row)*8) = v;
      }
    }
  }

  // ---- bulk trajectory store: block == batch b, fully coalesced ----
  __syncthreads();
  {
    const float* trajf = reinterpret_cast<const float*>(lds + TRAJ_OFF);
    const size_t ob = (size_t)blockIdx.x * (T_LEN*256);
    for (int i=tid; i<T_LEN*256; i+=512) out[ob + i] = trajf[i];
  }
}

extern "C" void kernel_launch(void* const* d_in, const int* in_sizes, int n_in,
                              void* d_out, int out_size, void* d_ws, size_t ws_size,
                              hipStream_t stream) {
  const float* h_obs     = (const float*)d_in[0];
  const float* z         = (const float*)d_in[1];
  const float* start_pos = (const float*)d_in[2];
  const float* W_in      = (const float*)d_in[3];
  const float* b_in      = (const float*)d_in[4];
  const float* W_ih      = (const float*)d_in[5];
  const float* b_ih      = (const float*)d_in[6];
  const float* W_hh      = (const float*)d_in[7];
  const float* b_hh      = (const float*)d_in[8];
  const float* W_out     = (const float*)d_in[9];
  const float* b_out     = (const float*)d_in[10];
  // pred_len (d_in[11]) fixed at 30.

  char* ws = (char*)d_ws;
  __bf16* WcT  = (__bf16*)ws;                              // 384*320*2 = 245760
  float*  cvec = (float*)(ws + 245760);                    // 384*4     = 1536
  float*  P2G  = (float*)(ws + 247296);                    // 768*4     = 3072
  __bf16* WT   = (__bf16*)(ws + 250368);                   // 512*136*2 = 139264

  prep_wc <<<20,  384, 0, stream>>>(W_in, W_ih, WcT);
  prep_vec<<<1,   384, 0, stream>>>(W_in, b_in, W_ih, b_ih, b_hh, b_out, cvec, P2G);
  prep_wt <<<512, 192, 0, stream>>>(W_hh, W_out, P2G, WT);
  decoder <<<256, 512, 0, stream>>>(h_obs, z, start_pos, b_hh, W_out, b_out,
                                    WcT, cvec, WT, (float*)d_out);
}

// Round 7
// 295.154 us; speedup vs baseline: 1.2166x; 1.2166x over previous
//
#include <hip/hip_runtime.h>
#include <hip/hip_bf16.h>

// RecurrentDecoder: B=256,N=128,D=256,Z=64,H=128, pred_len=30
// Rank-2 fold (verified R4): gate args accumulate entirely in MFMA.
//   W~[j] = scl_j*W_hh[j] + P2Gs0[j]*Wout[0] + P2Gs1[j]*Wout[1]
//   K-slots 128,129 of state rows hold pos_{t-1}(bf16); cvec carries b_out*P2Gs.
// R7: R4 skeleton, but G stays f32x4 and is consumed ONLY as MFMA C-init ->
// AGPR-resident (R2-style codegen, no arch-VGPR cost). st packed to bf16
// pairs. Arch demand ~122 < 128 -> no scratch spill (R4/R5 spilled 16-35MB
// because packed-G bit-ops forced G into arch VGPRs).

#define T_LEN 30
#define H_    128
#define G3_   384
#define KIN_  320
#define S2B   272                 // bytes per state row (136 bf16 elems, 130 used)
#define HB    (64*S2B)            // 17408 per ping-pong buffer
#define TRAJ_OFF (2*HB)           // 34816
#define LDS_BYTES (TRAJ_OFF + T_LEN*64*8)  // + 15360 = 50176

#define SCL_RZ -1.44269504088896341f
#define SCL_N   2.88539008177792681f

typedef float  f32x4 __attribute__((ext_vector_type(4)));
typedef __bf16 b16x8 __attribute__((ext_vector_type(8)));
typedef unsigned u32x4 __attribute__((ext_vector_type(4)));

#define MFMA16(a,b,c) __builtin_amdgcn_mfma_f32_16x16x32_bf16((a),(b),(c),0,0,0)

__device__ __forceinline__ b16x8 pack8s(const float* p, float s){
  b16x8 r;
  #pragma unroll
  for (int i=0;i<8;i++) r[i] = (__bf16)(s*p[i]);
  return r;
}
__device__ __forceinline__ unsigned pk2(float a, float b){
  __bf16 x=(__bf16)a, y=(__bf16)b;
  unsigned short ux=__builtin_bit_cast(unsigned short,x);
  unsigned short uy=__builtin_bit_cast(unsigned short,y);
  return (unsigned)ux | ((unsigned)uy<<16);
}
__device__ __forceinline__ f32x4 unpk2(unsigned lo, unsigned hi){
  f32x4 r;
  r[0]=__builtin_bit_cast(float, lo<<16);
  r[1]=__builtin_bit_cast(float, lo&0xFFFF0000u);
  r[2]=__builtin_bit_cast(float, hi<<16);
  r[3]=__builtin_bit_cast(float, hi&0xFFFF0000u);
  return r;
}
__device__ __forceinline__ b16x8 fragu(unsigned v){
  u32x4 t = {v,0u,0u,0u};
  return __builtin_bit_cast(b16x8, t);
}

// ---- prep 1: WcT[j][k] = scl_j * sum_m W_in[k][m]*W_ih[j][m]  (384x320 bf16) ----
__global__ void prep_wc(const float* __restrict__ W_in, const float* __restrict__ W_ih,
                        __bf16* __restrict__ WcT){
  __shared__ float win[H_][16];
  int k0 = blockIdx.x << 4;
  for (int i=threadIdx.x; i<16*H_; i+=384){
    int kk = i>>7, m = i&127;
    win[m][kk] = W_in[(size_t)(k0+kk)*H_ + m];
  }
  __syncthreads();
  int j = threadIdx.x;
  const float* wr = W_ih + (size_t)j*H_;
  float acc[16];
  #pragma unroll
  for (int kk=0;kk<16;kk++) acc[kk]=0.f;
  for (int m=0;m<H_;m++){
    float wv = wr[m];
    #pragma unroll
    for (int kk=0;kk<16;kk++) acc[kk] = fmaf(wv, win[m][kk], acc[kk]);
  }
  float scl = (j < 2*H_) ? SCL_RZ : SCL_N;
  #pragma unroll
  for (int kk=0;kk<16;kk++) WcT[(size_t)j*KIN_ + k0 + kk] = (__bf16)(scl*acc[kk]);
}

// ---- prep 2: cvec'(b_out-folded), P2Gs (scaled) ----
__global__ void prep_vec(const float* __restrict__ W_in, const float* __restrict__ b_in,
                         const float* __restrict__ W_ih, const float* __restrict__ b_ih,
                         const float* __restrict__ b_hh, const float* __restrict__ b_out,
                         float* __restrict__ cvec, float* __restrict__ P2G){
  int j = threadIdx.x;                      // 0..383
  const float* wr = W_ih + (size_t)j*H_;
  float s  = b_ih[j] + (j < 2*H_ ? b_hh[j] : 0.f);
  float p0 = 0.f, p1 = 0.f;
  #pragma unroll 8
  for (int m=0;m<H_;m++){
    float wv = wr[m];
    s  += b_in[m]*wv;
    p0 += W_in[(size_t)KIN_*H_ + m]*wv;
    p1 += W_in[(size_t)(KIN_+1)*H_ + m]*wv;
  }
  float scl = (j < 2*H_) ? SCL_RZ : SCL_N;
  float p0s = scl*p0, p1s = scl*p1;
  P2G[j] = p0s; P2G[G3_ + j] = p1s;
  cvec[j] = scl*s + b_out[0]*p0s + b_out[1]*p1s;   // b_out*P2G fold
}

// ---- prep 3: WT[512][136] bf16 — sets {0:r,1:z,2:an,3:inn} ----
__global__ void prep_wt(const float* __restrict__ W_hh, const float* __restrict__ W_out,
                        const float* __restrict__ P2G, __bf16* __restrict__ WT){
  int jp = blockIdx.x;                 // 0..511
  int set = jp >> 7, col = jp & 127;
  int j = (set==0) ? col : (set==1) ? H_+col : 2*H_+col;
  float p0 = P2G[j], p1 = P2G[G3_+j];  // scaled
  int k = threadIdx.x;
  if (k >= 136) return;
  float v = 0.f;
  if (k < 128){
    if (set<=1)      v = SCL_RZ*W_hh[(size_t)j*H_+k] + p0*W_out[k] + p1*W_out[H_+k];
    else if (set==2) v = SCL_N *W_hh[(size_t)j*H_+k];
    else             v = p0*W_out[k] + p1*W_out[H_+k];
  } else if (k==128){ v = (set==2)? 0.f : p0; }
  else if (k==129){ v = (set==2)? 0.f : p1; }
  WT[(size_t)jp*136 + k] = (__bf16)v;
}

// ---- decoder: 512 blocks x 512 threads, 64 rows/block ----
__global__ __launch_bounds__(512, 2)
void decoder(const float* __restrict__ h_obs, const float* __restrict__ zin,
             const float* __restrict__ start_pos,
             const float* __restrict__ b_hh, const float* __restrict__ W_out,
             const float* __restrict__ b_out,
             const __bf16* __restrict__ WcT, const float* __restrict__ cvec,
             const __bf16* __restrict__ WT, float* __restrict__ out)
{
  __shared__ __align__(16) char lds[LDS_BYTES];
  __bf16* stg = (__bf16*)lds;                 // [64][328] prologue staging (42KB ok? 64*328*2=41984 < 50176)

  const int tid  = threadIdx.x;
  const int lane = tid & 63;
  const int w    = tid >> 6;
  const int l15  = lane & 15;
  const int lhi  = lane >> 4;
  const int R0   = blockIdx.x << 6;           // 64 rows per block
  const int hcol = (w<<4) + l15;
  const int jr = hcol, jz = H_ + hcol, jn = 2*H_ + hcol;
  const int oc = l15 & 1;
  const bool desig = (w < 4);
  const int gd = w >> 1, md = w & 1;

  // ---- stage base tile (64 x 320 f32 -> bf16, stride 328) ----
  {
    const float4* src = reinterpret_cast<const float4*>(h_obs) + (size_t)R0*64;
    #pragma unroll
    for (int i=0;i<8;i++){
      int k = tid + (i<<9);
      float4 v = src[k];
      int r = k>>6, c = (k&63)<<2;
      __bf16* d = &stg[r*328 + c];
      d[0]=(__bf16)v.x; d[1]=(__bf16)v.y; d[2]=(__bf16)v.z; d[3]=(__bf16)v.w;
    }
    const float4* srcz = reinterpret_cast<const float4*>(zin) + (size_t)R0*16;
    #pragma unroll
    for (int i=0;i<2;i++){
      int k = tid + (i<<9);
      float4 v = srcz[k];
      int r = k>>4, c = 256 + ((k&15)<<2);
      __bf16* d = &stg[r*328 + c];
      d[0]=(__bf16)v.x; d[1]=(__bf16)v.y; d[2]=(__bf16)v.z; d[3]=(__bf16)v.w;
    }
  }

  // ---- scalar constants ----
  const float bo0 = b_out[0], bo1 = b_out[1];
  const float bo  = oc ? bo1 : bo0;
  const float bhn = SCL_N * b_hh[2*H_ + hcol];
  const f32x4 bhnvec = (f32x4){bhn,bhn,bhn,bhn};
  const f32x4 bovec  = (f32x4){bo,bo,bo,bo};

  float px[4]={0,0,0,0}, py[4]={0,0,0,0};
  if (desig){
    #pragma unroll
    for (int q=0;q<4;q++){
      int r = R0 + (gd<<5) + (md<<4) + (lhi<<2) + q;
      px[q] = start_pos[2*r]   - bo0;   // master init = pos0 - b_out
      py[q] = start_pos[2*r+1] - bo1;
    }
  }

  __syncthreads();

  // ---- prologue: G = base @ Wc + cvec' (K=320), KEPT AS f32x4 (AGPR) ----
  f32x4 G[2][3][2];
  {
    float cr = cvec[jr], cz = cvec[jz], cn = cvec[jn];
    #pragma unroll
    for (int g=0; g<2; g++){
      G[g][0][0] = (f32x4){cr,cr,cr,cr}; G[g][0][1] = G[g][0][0];
      G[g][1][0] = (f32x4){cz,cz,cz,cz}; G[g][1][1] = G[g][1][0];
      G[g][2][0] = (f32x4){cn,cn,cn,cn}; G[g][2][1] = G[g][2][0];
    }
    #pragma unroll 1
    for (int kk=0; kk<10; kk++){
      const int ko = (kk<<5) + (lhi<<3);
      b16x8 br = *reinterpret_cast<const b16x8*>(WcT + (size_t)jr*KIN_ + ko);
      b16x8 bz = *reinterpret_cast<const b16x8*>(WcT + (size_t)jz*KIN_ + ko);
      b16x8 bn = *reinterpret_cast<const b16x8*>(WcT + (size_t)jn*KIN_ + ko);
      #pragma unroll
      for (int g=0; g<2; g++){
        b16x8 a0 = *reinterpret_cast<const b16x8*>(&stg[(g*32   +l15)*328 + ko]);
        b16x8 a1 = *reinterpret_cast<const b16x8*>(&stg[(g*32+16+l15)*328 + ko]);
        G[g][0][0] = MFMA16(a0, br, G[g][0][0]); G[g][0][1] = MFMA16(a1, br, G[g][0][1]);
        G[g][1][0] = MFMA16(a0, bz, G[g][1][0]); G[g][1][1] = MFMA16(a1, bz, G[g][1][1]);
        G[g][2][0] = MFMA16(a0, bn, G[g][2][0]); G[g][2][1] = MFMA16(a1, bn, G[g][2][1]);
      }
    }
  }

  // ---- persistent B-fragments ----
  b16x8 Br[4],Bz[4],Ban[4],Binn[4],Bo[4];
  #pragma unroll
  for (int kk=0;kk<4;kk++){
    const int ko = kk*32 + lhi*8;
    Br[kk]   = *reinterpret_cast<const b16x8*>(WT + (size_t)(      hcol)*136 + ko);
    Bz[kk]   = *reinterpret_cast<const b16x8*>(WT + (size_t)(128 + hcol)*136 + ko);
    Ban[kk]  = *reinterpret_cast<const b16x8*>(WT + (size_t)(256 + hcol)*136 + ko);
    Binn[kk] = *reinterpret_cast<const b16x8*>(WT + (size_t)(384 + hcol)*136 + ko);
    Bo[kk]   = pack8s(W_out + (size_t)oc*H_ + ko, 1.0f);
  }
  const b16x8 Br4 = fragu(lhi==0 ? *reinterpret_cast<const unsigned*>(WT + (size_t)(      hcol)*136 + 128) : 0u);
  const b16x8 Bz4 = fragu(lhi==0 ? *reinterpret_cast<const unsigned*>(WT + (size_t)(128 + hcol)*136 + 128) : 0u);
  const b16x8 Bi4 = fragu(lhi==0 ? *reinterpret_cast<const unsigned*>(WT + (size_t)(384 + hcol)*136 + 128) : 0u);

  __syncthreads();   // staging dead; hbuf region live from here

  // ---- init buf0: zero h slots, owners write pos slots ----
  for (int i=tid; i<4096; i+=512){
    int r = i>>6, dw = i&63;
    *reinterpret_cast<unsigned*>(lds + r*S2B + dw*4) = 0u;
  }
  if (desig && l15==0){
    #pragma unroll
    for (int q=0;q<4;q++){
      int row = (gd<<5) + (md<<4) + (lhi<<2) + q;
      *reinterpret_cast<unsigned*>(lds + row*S2B + 256) = pk2(px[q], py[q]);
    }
  }

  // packed bf16 state: stp[g][m][pair] = (h[2p],h[2p+1])
  unsigned stp[2][2][2];
  #pragma unroll
  for (int g=0;g<2;g++)
    #pragma unroll
    for (int m=0;m<2;m++){ stp[g][m][0]=0u; stp[g][m][1]=0u; }

  const unsigned rdb = (unsigned)(l15*S2B + lhi*16);

  int cur = 0;
  #pragma unroll 1
  for (int t=0; t<T_LEN; ++t){
    __syncthreads();
    const char* rb = lds + cur*HB;
    char*       wb = lds + (cur^1)*HB;

    #pragma unroll
    for (int g=0; g<2; ++g){
      const char* rg_ = rb + g*(32*S2B);
      char*       wg_ = wb + g*(32*S2B);

      f32x4 ar0 = G[g][0][0], ar1 = G[g][0][1];
      f32x4 az0 = G[g][1][0], az1 = G[g][1][1];
      f32x4 ai0 = G[g][2][0], ai1 = G[g][2][1];
      f32x4 an0 = bhnvec, an1 = bhnvec;

      #pragma unroll
      for (int kk=0;kk<4;kk++){
        b16x8 a0 = *reinterpret_cast<const b16x8*>(rg_ + rdb + kk*64);
        b16x8 a1 = *reinterpret_cast<const b16x8*>(rg_ + rdb + 16*S2B + kk*64);
        ar0 = MFMA16(a0,Br[kk],ar0);   ar1 = MFMA16(a1,Br[kk],ar1);
        az0 = MFMA16(a0,Bz[kk],az0);   az1 = MFMA16(a1,Bz[kk],az1);
        an0 = MFMA16(a0,Ban[kk],an0);  an1 = MFMA16(a1,Ban[kk],an1);
        ai0 = MFMA16(a0,Binn[kk],ai0); ai1 = MFMA16(a1,Binn[kk],ai1);
      }
      {
        unsigned pp0 = *reinterpret_cast<const unsigned*>(rg_ + l15*S2B + 256);
        unsigned pp1 = *reinterpret_cast<const unsigned*>(rg_ + (16+l15)*S2B + 256);
        b16x8 a40 = fragu(lhi==0 ? pp0 : 0u);
        b16x8 a41 = fragu(lhi==0 ? pp1 : 0u);
        ar0 = MFMA16(a40,Br4,ar0); ar1 = MFMA16(a41,Br4,ar1);
        az0 = MFMA16(a40,Bz4,az0); az1 = MFMA16(a41,Bz4,az1);
        ai0 = MFMA16(a40,Bi4,ai0); ai1 = MFMA16(a41,Bi4,ai1);
      }

      if (desig && gd == g){
        f32x4 d = bovec;
        if (md==0){
          #pragma unroll
          for (int kk=0;kk<4;kk++){
            b16x8 fk = *reinterpret_cast<const b16x8*>(rg_ + rdb + kk*64);
            d = MFMA16(fk,Bo[kk],d);
          }
        } else {
          #pragma unroll
          for (int kk=0;kk<4;kk++){
            b16x8 fk = *reinterpret_cast<const b16x8*>(rg_ + rdb + 16*S2B + kk*64);
            d = MFMA16(fk,Bo[kk],d);
          }
        }
        #pragma unroll
        for (int q=0;q<4;q++){
          float dme  = d[q];
          float doth = __shfl_xor(dme, 1);
          px[q] += oc ? doth : dme;
          py[q] += oc ? dme  : doth;
        }
        if (l15==0){
          #pragma unroll
          for (int q=0;q<4;q++){
            int row = (gd<<5) + (md<<4) + (lhi<<2) + q;
            if (t > 0){
              float2 v; v.x = px[q]; v.y = py[q];
              *reinterpret_cast<float2*>(lds + TRAJ_OFF + ((t-1)*64 + row)*8) = v;
            }
            *reinterpret_cast<unsigned*>(wb + row*S2B + 256) = pk2(px[q], py[q]);
          }
        }
      }

      // gates -> h_{t+1}
      #pragma unroll
      for (int m=0;m<2;m++){
        f32x4 Ar = m? ar1:ar0, Az = m? az1:az0, An = m? an1:an0, Ai = m? ai1:ai0;
        f32x4 stv = unpk2(stp[g][m][0], stp[g][m][1]);
        float hq[4];
        #pragma unroll
        for (int q=0;q<4;q++){
          float rgt = __builtin_amdgcn_rcpf(1.f + __builtin_amdgcn_exp2f(Ar[q]));
          float zgt = __builtin_amdgcn_rcpf(1.f + __builtin_amdgcn_exp2f(Az[q]));
          float na  = fmaf(rgt, An[q], Ai[q]);
          float nn  = fmaf(-2.f, __builtin_amdgcn_rcpf(1.f + __builtin_amdgcn_exp2f(na)), 1.f);
          float h   = fmaf(zgt, stv[q] - nn, nn);
          hq[q] = h;
          *reinterpret_cast<__bf16*>(wg_ + ((m<<4)+(lhi<<2)+q)*S2B + hcol*2) = (__bf16)h;
        }
        stp[g][m][0] = pk2(hq[0], hq[1]);
        stp[g][m][1] = pk2(hq[2], hq[3]);
      }
    }
    cur ^= 1;
  }

  // ---- epilogue: final delta -> traj[29] ----
  __syncthreads();
  if (desig){
    const char* rg_ = lds + cur*HB + gd*(32*S2B);
    const unsigned dbase = (unsigned)((md*16 + l15)*S2B + lhi*16);
    f32x4 d = bovec;
    #pragma unroll
    for (int kk=0;kk<4;kk++){
      b16x8 fk = *reinterpret_cast<const b16x8*>(rg_ + dbase + kk*64);
      d = MFMA16(fk, Bo[kk], d);
    }
    #pragma unroll
    for (int q=0;q<4;q++){
      float dme  = d[q];
      float doth = __shfl_xor(dme, 1);
      px[q] += oc ? doth : dme;
      py[q] += oc ? dme  : doth;
    }
    if (l15==0){
      #pragma unroll
      for (int q=0;q<4;q++){
        int row = (gd<<5) + (md<<4) + (lhi<<2) + q;
        float2 v; v.x = px[q]; v.y = py[q];
        *reinterpret_cast<float2*>(lds + TRAJ_OFF + ((T_LEN-1)*64 + row)*8) = v;
      }
    }
  }

  // ---- bulk trajectory store (coalesced) ----
  __syncthreads();
  {
    const float* trajf = reinterpret_cast<const float*>(lds + TRAJ_OFF);
    const size_t ob  = ((size_t)(R0>>7)*T_LEN)<<8;
    const int    n02 = (R0 & 127)<<1;
    for (int i=tid; i<T_LEN*128; i+=512){
      int tt = i>>7, j = i&127;
      out[ob + (size_t)tt*256 + n02 + j] = trajf[i];
    }
  }
}

extern "C" void kernel_launch(void* const* d_in, const int* in_sizes, int n_in,
                              void* d_out, int out_size, void* d_ws, size_t ws_size,
                              hipStream_t stream) {
  const float* h_obs     = (const float*)d_in[0];
  const float* z         = (const float*)d_in[1];
  const float* start_pos = (const float*)d_in[2];
  const float* W_in      = (const float*)d_in[3];
  const float* b_in      = (const float*)d_in[4];
  const float* W_ih      = (const float*)d_in[5];
  const float* b_ih      = (const float*)d_in[6];
  const float* W_hh      = (const float*)d_in[7];
  const float* b_hh      = (const float*)d_in[8];
  const float* W_out     = (const float*)d_in[9];
  const float* b_out     = (const float*)d_in[10];
  // pred_len (d_in[11]) fixed at 30.

  char* ws = (char*)d_ws;
  __bf16* WcT  = (__bf16*)ws;                              // 384*320*2 = 245760
  float*  cvec = (float*)(ws + 245760);                    // 384*4     = 1536
  float*  P2G  = (float*)(ws + 247296);                    // 768*4     = 3072
  __bf16* WT   = (__bf16*)(ws + 250368);                   // 512*136*2 = 139264

  prep_wc <<<20,  384, 0, stream>>>(W_in, W_ih, WcT);
  prep_vec<<<1,   384, 0, stream>>>(W_in, b_in, W_ih, b_ih, b_hh, b_out, cvec, P2G);
  prep_wt <<<512, 192, 0, stream>>>(W_hh, W_out, P2G, WT);
  decoder <<<512, 512, 0, stream>>>(h_obs, z, start_pos, b_hh, W_out, b_out,
                                    WcT, cvec, WT, (float*)d_out);
}

// Round 8
// 292.507 us; speedup vs baseline: 1.2277x; 1.0091x over previous
//
#include <hip/hip_runtime.h>
#include <hip/hip_bf16.h>

// RecurrentDecoder: B=256,N=128,D=256,Z=64,H=128, pred_len=30
// R8: two-phase step with exact pos_t in LDS.
//   Phase A: gh MFMAs (plain scaled W_hh for r,z,n) + desig waves compute
//            delta_t = h_t@Wout + b_out, update fp32 pos, publish pk2(pos_t)
//            to a 256B LDS pos region.  barrier.
//   Phase B: tail MFMA (K-slots 0,1 = pos_t) adds pos_t@P2Gs to r,z,inn
//            gate args; gates; write h_{t+1}.
// This removes the rank-2 fold from the recurrent weights (Binn set gone,
// -16 arch VGPRs, -16 MFMA/wave/step) -> arch demand ~108 < 128 -> no spill
// (R7 still spilled ~8MB: WRITE 16.1MB vs 7.9MB output).

#define T_LEN 30
#define H_    128
#define G3_   384
#define KIN_  320
#define S2B   272                 // state row stride (2-way bank alias = free)
#define HB    (64*S2B)            // 17408 per ping-pong buffer
#define TRAJ_OFF (2*HB)           // 34816
#define POS_OFF  (TRAJ_OFF + T_LEN*64*8)   // 50176
#define LDS_BYTES (POS_OFF + 256)          // 50432

#define SCL_RZ -1.44269504088896341f
#define SCL_N   2.88539008177792681f

typedef float  f32x4 __attribute__((ext_vector_type(4)));
typedef __bf16 b16x8 __attribute__((ext_vector_type(8)));
typedef unsigned u32x4 __attribute__((ext_vector_type(4)));

#define MFMA16(a,b,c) __builtin_amdgcn_mfma_f32_16x16x32_bf16((a),(b),(c),0,0,0)

__device__ __forceinline__ b16x8 pack8s(const float* p, float s){
  b16x8 r;
  #pragma unroll
  for (int i=0;i<8;i++) r[i] = (__bf16)(s*p[i]);
  return r;
}
__device__ __forceinline__ unsigned pk2(float a, float b){
  __bf16 x=(__bf16)a, y=(__bf16)b;
  unsigned short ux=__builtin_bit_cast(unsigned short,x);
  unsigned short uy=__builtin_bit_cast(unsigned short,y);
  return (unsigned)ux | ((unsigned)uy<<16);
}
__device__ __forceinline__ f32x4 unpk2(unsigned lo, unsigned hi){
  f32x4 r;
  r[0]=__builtin_bit_cast(float, lo<<16);
  r[1]=__builtin_bit_cast(float, lo&0xFFFF0000u);
  r[2]=__builtin_bit_cast(float, hi<<16);
  r[3]=__builtin_bit_cast(float, hi&0xFFFF0000u);
  return r;
}
__device__ __forceinline__ b16x8 fragu(unsigned v){
  u32x4 t = {v,0u,0u,0u};
  return __builtin_bit_cast(b16x8, t);
}

// ---- prep 1: WcT[j][k] = scl_j * sum_m W_in[k][m]*W_ih[j][m]  (384x320 bf16) ----
__global__ void prep_wc(const float* __restrict__ W_in, const float* __restrict__ W_ih,
                        __bf16* __restrict__ WcT){
  __shared__ float win[H_][16];
  int k0 = blockIdx.x << 4;
  for (int i=threadIdx.x; i<16*H_; i+=384){
    int kk = i>>7, m = i&127;
    win[m][kk] = W_in[(size_t)(k0+kk)*H_ + m];
  }
  __syncthreads();
  int j = threadIdx.x;
  const float* wr = W_ih + (size_t)j*H_;
  float acc[16];
  #pragma unroll
  for (int kk=0;kk<16;kk++) acc[kk]=0.f;
  for (int m=0;m<H_;m++){
    float wv = wr[m];
    #pragma unroll
    for (int kk=0;kk<16;kk++) acc[kk] = fmaf(wv, win[m][kk], acc[kk]);
  }
  float scl = (j < 2*H_) ? SCL_RZ : SCL_N;
  #pragma unroll
  for (int kk=0;kk<16;kk++) WcT[(size_t)j*KIN_ + k0 + kk] = (__bf16)(scl*acc[kk]);
}

// ---- prep 2: cvec (scaled, NO b_out fold), P2Gs (scaled) ----
__global__ void prep_vec(const float* __restrict__ W_in, const float* __restrict__ b_in,
                         const float* __restrict__ W_ih, const float* __restrict__ b_ih,
                         const float* __restrict__ b_hh, const float* __restrict__ b_out,
                         float* __restrict__ cvec, float* __restrict__ P2G){
  int j = threadIdx.x;                      // 0..383
  const float* wr = W_ih + (size_t)j*H_;
  float s  = b_ih[j] + (j < 2*H_ ? b_hh[j] : 0.f);
  float p0 = 0.f, p1 = 0.f;
  #pragma unroll 8
  for (int m=0;m<H_;m++){
    float wv = wr[m];
    s  += b_in[m]*wv;
    p0 += W_in[(size_t)KIN_*H_ + m]*wv;
    p1 += W_in[(size_t)(KIN_+1)*H_ + m]*wv;
  }
  float scl = (j < 2*H_) ? SCL_RZ : SCL_N;
  P2G[j] = scl*p0; P2G[G3_ + j] = scl*p1;
  cvec[j] = scl*s;
}

// ---- prep 3: WT[512][136] bf16 — sets {0:r,1:z,2:an,3:inn-tail} ----
// k<128: sets 0,1 = SCL_RZ*W_hh ; set 2 = SCL_N*W_hh ; set 3 = 0.
// k=128,129: (p0,p1) scaled pos->gate coeffs for sets 0,1,3; set 2 = 0.
__global__ void prep_wt(const float* __restrict__ W_hh, const float* __restrict__ W_out,
                        const float* __restrict__ P2G, __bf16* __restrict__ WT){
  int jp = blockIdx.x;                 // 0..511
  int set = jp >> 7, col = jp & 127;
  int j = (set==0) ? col : (set==1) ? H_+col : 2*H_+col;
  float p0 = P2G[j], p1 = P2G[G3_+j];  // scaled
  int k = threadIdx.x;
  if (k >= 136) return;
  float v = 0.f;
  if (k < 128){
    if (set==0 || set==1) v = SCL_RZ*W_hh[(size_t)j*H_+k];
    else if (set==2)      v = SCL_N *W_hh[(size_t)j*H_+k];
    else                  v = 0.f;
  } else if (k==128){ v = (set==2)? 0.f : p0; }
  else if (k==129){ v = (set==2)? 0.f : p1; }
  WT[(size_t)jp*136 + k] = (__bf16)v;
}

// ---- decoder: 512 blocks x 512 threads, 64 rows/block ----
__global__ __launch_bounds__(512, 2)
void decoder(const float* __restrict__ h_obs, const float* __restrict__ zin,
             const float* __restrict__ start_pos,
             const float* __restrict__ b_hh, const float* __restrict__ W_out,
             const float* __restrict__ b_out,
             const __bf16* __restrict__ WcT, const float* __restrict__ cvec,
             const __bf16* __restrict__ WT, float* __restrict__ out)
{
  __shared__ __align__(16) char lds[LDS_BYTES];
  __bf16* stg = (__bf16*)lds;                 // [64][328] prologue staging (41984B)

  const int tid  = threadIdx.x;
  const int lane = tid & 63;
  const int w    = tid >> 6;
  const int l15  = lane & 15;
  const int lhi  = lane >> 4;
  const int R0   = blockIdx.x << 6;           // 64 rows per block
  const int hcol = (w<<4) + l15;
  const int jr = hcol, jz = H_ + hcol, jn = 2*H_ + hcol;
  const int oc = l15 & 1;
  const bool desig = (w < 4);
  const int gd = w >> 1, md = w & 1;

  // ---- stage base tile (64 x 320 f32 -> bf16, stride 328) ----
  {
    const float4* src = reinterpret_cast<const float4*>(h_obs) + (size_t)R0*64;
    #pragma unroll
    for (int i=0;i<8;i++){
      int k = tid + (i<<9);
      float4 v = src[k];
      int r = k>>6, c = (k&63)<<2;
      __bf16* d = &stg[r*328 + c];
      d[0]=(__bf16)v.x; d[1]=(__bf16)v.y; d[2]=(__bf16)v.z; d[3]=(__bf16)v.w;
    }
    const float4* srcz = reinterpret_cast<const float4*>(zin) + (size_t)R0*16;
    #pragma unroll
    for (int i=0;i<2;i++){
      int k = tid + (i<<9);
      float4 v = srcz[k];
      int r = k>>4, c = 256 + ((k&15)<<2);
      __bf16* d = &stg[r*328 + c];
      d[0]=(__bf16)v.x; d[1]=(__bf16)v.y; d[2]=(__bf16)v.z; d[3]=(__bf16)v.w;
    }
  }

  // ---- scalar constants ----
  const float bo0 = b_out[0], bo1 = b_out[1];
  const float bo  = oc ? bo1 : bo0;
  const float bhn = SCL_N * b_hh[2*H_ + hcol];
  const f32x4 bhnvec = (f32x4){bhn,bhn,bhn,bhn};
  const f32x4 bovec  = (f32x4){bo,bo,bo,bo};

  float px[4]={0,0,0,0}, py[4]={0,0,0,0};
  if (desig){
    #pragma unroll
    for (int q=0;q<4;q++){
      int r = R0 + (gd<<5) + (md<<4) + (lhi<<2) + q;
      px[q] = start_pos[2*r]   - bo0;   // iter0 delta(+bo) restores start
      py[q] = start_pos[2*r+1] - bo1;
    }
  }

  __syncthreads();

  // ---- prologue: G = base @ Wc + cvec (K=320), kept f32x4 (AGPR) ----
  f32x4 G[2][3][2];
  {
    float cr = cvec[jr], cz = cvec[jz], cn = cvec[jn];
    #pragma unroll
    for (int g=0; g<2; g++){
      G[g][0][0] = (f32x4){cr,cr,cr,cr}; G[g][0][1] = G[g][0][0];
      G[g][1][0] = (f32x4){cz,cz,cz,cz}; G[g][1][1] = G[g][1][0];
      G[g][2][0] = (f32x4){cn,cn,cn,cn}; G[g][2][1] = G[g][2][0];
    }
    #pragma unroll 1
    for (int kk=0; kk<10; kk++){
      const int ko = (kk<<5) + (lhi<<3);
      b16x8 br = *reinterpret_cast<const b16x8*>(WcT + (size_t)jr*KIN_ + ko);
      b16x8 bz = *reinterpret_cast<const b16x8*>(WcT + (size_t)jz*KIN_ + ko);
      b16x8 bn = *reinterpret_cast<const b16x8*>(WcT + (size_t)jn*KIN_ + ko);
      #pragma unroll
      for (int g=0; g<2; g++){
        b16x8 a0 = *reinterpret_cast<const b16x8*>(&stg[(g*32   +l15)*328 + ko]);
        b16x8 a1 = *reinterpret_cast<const b16x8*>(&stg[(g*32+16+l15)*328 + ko]);
        G[g][0][0] = MFMA16(a0, br, G[g][0][0]); G[g][0][1] = MFMA16(a1, br, G[g][0][1]);
        G[g][1][0] = MFMA16(a0, bz, G[g][1][0]); G[g][1][1] = MFMA16(a1, bz, G[g][1][1]);
        G[g][2][0] = MFMA16(a0, bn, G[g][2][0]); G[g][2][1] = MFMA16(a1, bn, G[g][2][1]);
      }
    }
  }

  // ---- persistent B-fragments (3 main sets + Bo + 3 tail words) ----
  b16x8 Br[4],Bz[4],Ban[4],Bo[4];
  #pragma unroll
  for (int kk=0;kk<4;kk++){
    const int ko = kk*32 + lhi*8;
    Br[kk]   = *reinterpret_cast<const b16x8*>(WT + (size_t)(      hcol)*136 + ko);
    Bz[kk]   = *reinterpret_cast<const b16x8*>(WT + (size_t)(128 + hcol)*136 + ko);
    Ban[kk]  = *reinterpret_cast<const b16x8*>(WT + (size_t)(256 + hcol)*136 + ko);
    Bo[kk]   = pack8s(W_out + (size_t)oc*H_ + ko, 1.0f);
  }
  const b16x8 Br4 = fragu(lhi==0 ? *reinterpret_cast<const unsigned*>(WT + (size_t)(      hcol)*136 + 128) : 0u);
  const b16x8 Bz4 = fragu(lhi==0 ? *reinterpret_cast<const unsigned*>(WT + (size_t)(128 + hcol)*136 + 128) : 0u);
  const b16x8 Bi4 = fragu(lhi==0 ? *reinterpret_cast<const unsigned*>(WT + (size_t)(384 + hcol)*136 + 128) : 0u);

  __syncthreads();   // staging dead; hbuf region live from here

  // ---- init buf0: zero h slots (cols 0..127) ----
  for (int i=tid; i<4096; i+=512){
    int r = i>>6, dw = i&63;
    *reinterpret_cast<unsigned*>(lds + r*S2B + dw*4) = 0u;
  }

  // packed bf16 state
  unsigned stp[2][2][2];
  #pragma unroll
  for (int g=0;g<2;g++)
    #pragma unroll
    for (int m=0;m<2;m++){ stp[g][m][0]=0u; stp[g][m][1]=0u; }

  const unsigned rdb = (unsigned)(l15*S2B + lhi*16);

  int cur = 0;
  #pragma unroll 1
  for (int t=0; t<T_LEN; ++t){
    __syncthreads();
    const char* rb = lds + cur*HB;
    char*       wb = lds + (cur^1)*HB;

    f32x4 AR[2][2], AZ[2][2], AN[2][2];

    // ---- phase A: gh MFMAs; desig computes delta_t, publishes pos_t ----
    #pragma unroll
    for (int g=0; g<2; ++g){
      const char* rg_ = rb + g*(32*S2B);
      const bool own = (desig && gd == g);
      f32x4 ar0 = G[g][0][0], ar1 = G[g][0][1];
      f32x4 az0 = G[g][1][0], az1 = G[g][1][1];
      f32x4 an0 = bhnvec,     an1 = bhnvec;
      f32x4 dAcc = bovec;
      #pragma unroll
      for (int kk=0;kk<4;kk++){
        b16x8 a0 = *reinterpret_cast<const b16x8*>(rg_ + rdb + kk*64);
        b16x8 a1 = *reinterpret_cast<const b16x8*>(rg_ + rdb + 16*S2B + kk*64);
        ar0 = MFMA16(a0,Br[kk],ar0);   ar1 = MFMA16(a1,Br[kk],ar1);
        az0 = MFMA16(a0,Bz[kk],az0);   az1 = MFMA16(a1,Bz[kk],az1);
        an0 = MFMA16(a0,Ban[kk],an0);  an1 = MFMA16(a1,Ban[kk],an1);
        if (own){ b16x8 am = md ? a1 : a0; dAcc = MFMA16(am, Bo[kk], dAcc); }
      }
      if (own){
        #pragma unroll
        for (int q=0;q<4;q++){
          float dme  = dAcc[q];
          float doth = __shfl_xor(dme, 1);
          px[q] += oc ? doth : dme;
          py[q] += oc ? dme  : doth;
        }
        if (l15==0){
          #pragma unroll
          for (int q=0;q<4;q++){
            int row = (gd<<5) + (md<<4) + (lhi<<2) + q;
            if (t > 0){
              float2 v; v.x = px[q]; v.y = py[q];
              *reinterpret_cast<float2*>(lds + TRAJ_OFF + ((t-1)*64 + row)*8) = v;
            }
            *reinterpret_cast<unsigned*>(lds + POS_OFF + row*4) = pk2(px[q], py[q]);
          }
        }
      }
      AR[g][0]=ar0; AR[g][1]=ar1;
      AZ[g][0]=az0; AZ[g][1]=az1;
      AN[g][0]=an0; AN[g][1]=an1;
    }

    __syncthreads();   // pos_t visible to all waves

    // ---- phase B: pos tail + gates -> h_{t+1} ----
    #pragma unroll
    for (int g=0; g<2; ++g){
      char* wg_ = wb + g*(32*S2B);
      unsigned pp0 = *reinterpret_cast<const unsigned*>(lds + POS_OFF + ((g<<5) + l15)*4);
      unsigned pp1 = *reinterpret_cast<const unsigned*>(lds + POS_OFF + ((g<<5) + 16 + l15)*4);
      b16x8 a40 = fragu(lhi==0 ? pp0 : 0u);
      b16x8 a41 = fragu(lhi==0 ? pp1 : 0u);
      f32x4 ar0 = MFMA16(a40,Br4,AR[g][0]), ar1 = MFMA16(a41,Br4,AR[g][1]);
      f32x4 az0 = MFMA16(a40,Bz4,AZ[g][0]), az1 = MFMA16(a41,Bz4,AZ[g][1]);
      f32x4 ai0 = MFMA16(a40,Bi4,G[g][2][0]), ai1 = MFMA16(a41,Bi4,G[g][2][1]);
      #pragma unroll
      for (int m=0;m<2;m++){
        f32x4 Ar = m? ar1:ar0, Az = m? az1:az0, Ai = m? ai1:ai0;
        f32x4 An = AN[g][m];
        f32x4 stv = unpk2(stp[g][m][0], stp[g][m][1]);
        float hq[4];
        #pragma unroll
        for (int q=0;q<4;q++){
          float rgt = __builtin_amdgcn_rcpf(1.f + __builtin_amdgcn_exp2f(Ar[q]));
          float zgt = __builtin_amdgcn_rcpf(1.f + __builtin_amdgcn_exp2f(Az[q]));
          float na  = fmaf(rgt, An[q], Ai[q]);
          float nn  = fmaf(-2.f, __builtin_amdgcn_rcpf(1.f + __builtin_amdgcn_exp2f(na)), 1.f);
          float h   = fmaf(zgt, stv[q] - nn, nn);
          hq[q] = h;
          *reinterpret_cast<__bf16*>(wg_ + ((m<<4)+(lhi<<2)+q)*S2B + hcol*2) = (__bf16)h;
        }
        stp[g][m][0] = pk2(hq[0], hq[1]);
        stp[g][m][1] = pk2(hq[2], hq[3]);
      }
    }
    cur ^= 1;
  }

  // ---- epilogue: final delta -> traj[29] ----
  __syncthreads();
  if (desig){
    const char* rg_ = lds + cur*HB + gd*(32*S2B);
    const unsigned dbase = (unsigned)((md*16 + l15)*S2B + lhi*16);
    f32x4 d = bovec;
    #pragma unroll
    for (int kk=0;kk<4;kk++){
      b16x8 fk = *reinterpret_cast<const b16x8*>(rg_ + dbase + kk*64);
      d = MFMA16(fk, Bo[kk], d);
    }
    #pragma unroll
    for (int q=0;q<4;q++){
      float dme  = d[q];
      float doth = __shfl_xor(dme, 1);
      px[q] += oc ? doth : dme;
      py[q] += oc ? dme  : doth;
    }
    if (l15==0){
      #pragma unroll
      for (int q=0;q<4;q++){
        int row = (gd<<5) + (md<<4) + (lhi<<2) + q;
        float2 v; v.x = px[q]; v.y = py[q];
        *reinterpret_cast<float2*>(lds + TRAJ_OFF + ((T_LEN-1)*64 + row)*8) = v;
      }
    }
  }

  // ---- bulk trajectory store (coalesced) ----
  __syncthreads();
  {
    const float* trajf = reinterpret_cast<const float*>(lds + TRAJ_OFF);
    const size_t ob  = ((size_t)(R0>>7)*T_LEN)<<8;
    const int    n02 = (R0 & 127)<<1;
    for (int i=tid; i<T_LEN*128; i+=512){
      int tt = i>>7, j = i&127;
      out[ob + (size_t)tt*256 + n02 + j] = trajf[i];
    }
  }
}

extern "C" void kernel_launch(void* const* d_in, const int* in_sizes, int n_in,
                              void* d_out, int out_size, void* d_ws, size_t ws_size,
                              hipStream_t stream) {
  const float* h_obs     = (const float*)d_in[0];
  const float* z         = (const float*)d_in[1];
  const float* start_pos = (const float*)d_in[2];
  const float* W_in      = (const float*)d_in[3];
  const float* b_in      = (const float*)d_in[4];
  const float* W_ih      = (const float*)d_in[5];
  const float* b_ih      = (const float*)d_in[6];
  const float* W_hh      = (const float*)d_in[7];
  const float* b_hh      = (const float*)d_in[8];
  const float* W_out     = (const float*)d_in[9];
  const float* b_out     = (const float*)d_in[10];
  // pred_len (d_in[11]) fixed at 30.

  char* ws = (char*)d_ws;
  __bf16* WcT  = (__bf16*)ws;                              // 384*320*2 = 245760
  float*  cvec = (float*)(ws + 245760);                    // 384*4     = 1536
  float*  P2G  = (float*)(ws + 247296);                    // 768*4     = 3072
  __bf16* WT   = (__bf16*)(ws + 250368);                   // 512*136*2 = 139264

  prep_wc <<<20,  384, 0, stream>>>(W_in, W_ih, WcT);
  prep_vec<<<1,   384, 0, stream>>>(W_in, b_in, W_ih, b_ih, b_hh, b_out, cvec, P2G);
  prep_wt <<<512, 192, 0, stream>>>(W_hh, W_out, P2G, WT);
  decoder <<<512, 512, 0, stream>>>(h_obs, z, start_pos, b_hh, W_out, b_out,
                                    WcT, cvec, WT, (float*)d_out);
}